// Round 5
// baseline (266.844 us; speedup 1.0000x reference)
//
#include <hip/hip_runtime.h>
#include <hip/hip_bf16.h>

typedef __attribute__((ext_vector_type(8))) __bf16   bf16x8;
typedef __attribute__((ext_vector_type(4))) _Float16 f16x4;
typedef __attribute__((ext_vector_type(4))) float    f32x4;
typedef __attribute__((ext_vector_type(4))) int      i32x4;

namespace {
constexpr int kB   = 16;
constexpr int kSQ  = 2048;
constexpr int kSK  = 2048;
constexpr int kD   = 64;
constexpr int kQB  = 16;     // q-rows per workgroup
constexpr int kNW  = 8;      // waves per workgroup
constexpr int kTPW = 16;     // 16-key tiles per wave (256 keys/wave)
constexpr int kCStride = 68; // ctx-partial row stride (floats)
constexpr float kScaleLog2e = 0.18033688011112042f; // (1/8)*log2(e)
}

// Register-resident-P fused attention (repack-free).
// wg = (batch, 16 q-rows); wave w owns keys [w*256, w*256+256).
// P1: swapped QK^T via mfma_f32_16x16x32_bf16 (A=K, B=Q) -> lane (l15,kg)
//     holds S[key=t*16+kg*4+r][q=l15]; mask via one dwordx4/lane; exp2;
//     P kept as f16x4[16] in VGPRs (32 regs).
// P2: attn = P*inv straight from regs (f32x4 stores).
// P3: PV via mfma_f32_16x16x16_f16: its B layout (col=l15, k=kg*4+e) is
//     EXACTLY the P1 output layout -> pb[t] is the B operand verbatim.
//     A = V^T (row=l15 -> d, k=kg*4+e -> key) scalar loads from L2-resident V.
// P4: cross-wave ctx reduce via small LDS stash, scale, store.
// LDS = 35 KB -> 2 wg/CU @ launch_bounds(512,4); fully unrolled P1 keeps
// many independent mask/K loads in flight per wave (latency hiding).
__global__ __launch_bounds__(512, 4)
void sdpa_regp(const float* __restrict__ Qg, const float* __restrict__ Kg,
               const float* __restrict__ Vg, const int* __restrict__ Mg,
               float* __restrict__ ctxOut, float* __restrict__ attnOut)
{
  __shared__ float sums[kNW][kQB];
  __shared__ __align__(16) float cpart[kNW][kQB][kCStride];

  const int tid  = threadIdx.x;
  const int wid  = tid >> 6;
  const int lane = tid & 63;
  const int l15  = lane & 15;
  const int kg   = lane >> 4;          // 0..3

  // XCD-bijective swizzle: 2048 wgs = 8 XCDs x 256 contiguous (2 batches/XCD).
  const int wg = (blockIdx.x & 7) * 256 + (blockIdx.x >> 3);
  const int b  = wg >> 7;              // 128 q-blocks per batch
  const int q0 = (wg & 127) * kQB;

  const float* Qb = Qg + (size_t)b * kSQ * kD;
  const float* Kb = Kg + (size_t)b * kSK * kD;
  const float* Vb = Vg + (size_t)b * kSK * kD;
  const int*   Mb = Mg + (size_t)b * kSQ * kSK;

  const int qrow  = q0 + l15;          // this lane's q-row
  const int kbase = wid * (kTPW * 16); // this wave's key range

  // Q fragment (B operand of swapped QK^T): col=l15=q, k=kg*8+e over D.
  bf16x8 qf0, qf1;
  {
    const float* qp = Qb + (size_t)qrow * kD + kg * 8;
#pragma unroll
    for (int e = 0; e < 8; ++e) { qf0[e] = (__bf16)qp[e]; qf1[e] = (__bf16)qp[32 + e]; }
  }
  const int* mrow = Mb + (size_t)qrow * kSK + kbase;

  // ---- P1: QK^T + mask + exp -> packed f16 P in registers ----
  f16x4 pb[kTPW];
  float lsum = 0.f;
#pragma unroll
  for (int t = 0; t < kTPW; ++t) {
    const int k0 = kbase + t * 16;
    const float* kp = Kb + (size_t)(k0 + l15) * kD + kg * 8;
    bf16x8 kf0, kf1;
#pragma unroll
    for (int e = 0; e < 8; ++e) { kf0[e] = (__bf16)kp[e]; kf1[e] = (__bf16)kp[32 + e]; }
    const i32x4 mv = *reinterpret_cast<const i32x4*>(mrow + t * 16 + kg * 4);
    f32x4 acc = {0.f, 0.f, 0.f, 0.f};
    acc = __builtin_amdgcn_mfma_f32_16x16x32_bf16(kf0, qf0, acc, 0, 0, 0);
    acc = __builtin_amdgcn_mfma_f32_16x16x32_bf16(kf1, qf1, acc, 0, 0, 0);
    // lane holds S[key = k0+kg*4+r][q = qrow], r=0..3
    f16x4 p4;
#pragma unroll
    for (int r = 0; r < 4; ++r) {
      const float pv = mv[r] ? 0.f : __builtin_amdgcn_exp2f(acc[r] * kScaleLog2e);
      lsum += pv;
      p4[r] = (_Float16)pv;
    }
    pb[t] = p4;
  }
  // row-sum: reduce over the 4 kg groups (lanes sharing l15)
  lsum += __shfl_xor(lsum, 16, 64);
  lsum += __shfl_xor(lsum, 32, 64);
  if (lane < 16) sums[wid][l15] = lsum;
  __syncthreads();

  float lden = 0.f;
#pragma unroll
  for (int w = 0; w < kNW; ++w) lden += sums[w][l15];
  const float inv = 1.0f / lden;

  // ---- P2: attn stores straight from registers ----
  {
    float* arow = attnOut + ((size_t)b * kSQ + qrow) * kSK + kbase;
#pragma unroll
    for (int t = 0; t < kTPW; ++t) {
      float4 o;
      o.x = (float)pb[t][0] * inv; o.y = (float)pb[t][1] * inv;
      o.z = (float)pb[t][2] * inv; o.w = (float)pb[t][3] * inv;
      *reinterpret_cast<float4*>(arow + t * 16 + kg * 4) = o;
    }
  }

  // ---- P3: PV via 16x16x16 f16 MFMA; pb[t] is the B operand verbatim ----
  // A = V^T: row=l15 -> d = dblk*16+l15; k = kg*4+e -> key = kbase+t*16+kg*4+e.
  // D: col=l15=q, row=kg*4+r -> d = dblk*16+kg*4+r.
  f32x4 cacc[4];
#pragma unroll
  for (int d = 0; d < 4; ++d) cacc[d] = f32x4{0.f, 0.f, 0.f, 0.f};
#pragma unroll
  for (int t = 0; t < kTPW; ++t) {
    const f16x4 pfrag = pb[t];
    const float* vw = Vb + (size_t)(kbase + t * 16 + kg * 4) * kD + l15;
#pragma unroll
    for (int dblk = 0; dblk < 4; ++dblk) {
      f16x4 vf;
#pragma unroll
      for (int e = 0; e < 4; ++e) vf[e] = (_Float16)vw[e * kD + dblk * 16];
      cacc[dblk] = __builtin_amdgcn_mfma_f32_16x16x16f16(vf, pfrag, cacc[dblk], 0, 0, 0);
    }
  }
  // lane holds ctx^T[d = dblk*16 + kg*4 + r][q = l15] partials
#pragma unroll
  for (int dblk = 0; dblk < 4; ++dblk)
    *reinterpret_cast<f32x4*>(&cpart[wid][l15][dblk * 16 + kg * 4]) = cacc[dblk];
  __syncthreads();

  // ---- P4: cross-wave reduce + scale + ctx store ----
  if (tid < kQB * 16) {
    const int q = tid >> 4;
    const int d = (tid & 15) * 4;
    float4 o = make_float4(0.f, 0.f, 0.f, 0.f);
#pragma unroll
    for (int w = 0; w < kNW; ++w) {
      const float4 p = *reinterpret_cast<const float4*>(&cpart[w][q][d]);
      o.x += p.x; o.y += p.y; o.z += p.z; o.w += p.w;
    }
    float l = 0.f;
#pragma unroll
    for (int w = 0; w < kNW; ++w) l += sums[w][q];
    const float iv = 1.0f / l;
    o.x *= iv; o.y *= iv; o.z *= iv; o.w *= iv;
    *reinterpret_cast<float4*>(ctxOut + ((size_t)b * kSQ + q0 + q) * kD + d) = o;
  }
}

extern "C" void kernel_launch(void* const* d_in, const int* in_sizes, int n_in,
                              void* d_out, int out_size, void* d_ws, size_t ws_size,
                              hipStream_t stream)
{
  const float* Q = (const float*)d_in[0];
  const float* K = (const float*)d_in[1];
  const float* V = (const float*)d_in[2];
  const int*   M = (const int*)d_in[3];   // bool mask pushed as 4-byte words
  float* ctx  = (float*)d_out;
  float* attn = (float*)d_out + (size_t)kB * kSQ * kD;

  dim3 grid(kB * (kSQ / kQB));  // 2048
  dim3 block(512);
  hipLaunchKernelGGL(sdpa_regp, grid, block, 0, stream, Q, K, V, M, ctx, attn);
}

// Round 6
// 211.995 us; speedup vs baseline: 1.2587x; 1.2587x over previous
//
#include <hip/hip_runtime.h>
#include <hip/hip_bf16.h>

typedef __attribute__((ext_vector_type(8))) __bf16   bf16x8;
typedef __attribute__((ext_vector_type(4))) _Float16 f16x4;
typedef __attribute__((ext_vector_type(4))) float    f32x4;
typedef __attribute__((ext_vector_type(4))) int      i32x4;
typedef __attribute__((ext_vector_type(8))) unsigned short u16x8;

namespace {
constexpr int kB   = 16;
constexpr int kSQ  = 2048;
constexpr int kSK  = 2048;
constexpr int kD   = 64;
constexpr int kQB  = 16;      // q-rows per workgroup
constexpr int kNW  = 4;       // waves per workgroup (256 threads)
constexpr int kTPW = 32;      // 16-key tiles per wave (512 keys/wave)
constexpr int kNT  = kSK / 16;            // 128 tiles per batch-row
constexpr int kCStride = 68;
constexpr float kScaleLog2e = 0.18033688011112042f; // (1/8)*log2(e)
// ws layout: Kp (bf16 frag-ordered) then Vp (f16 frag-ordered), 4 MB each.
constexpr size_t kKpElems = (size_t)kB * kNT * 2 * 64 * 8;  // ushort
constexpr size_t kVpOff   = kKpElems * 2;                   // bytes = 4 MB
}

// ---- setup kernel 1: K[b][key][d] f32 -> Kp fragment-ordered bf16 ----
// Kp[((b*kNT + kt)*2 + f)*64 + lane][8] ; lane=(kg*16+l15) holds
// K[kt*16+l15][f*32+kg*8 .. +8). Main-kernel load = 1 dwordx4/lane, 1 KB/wave.
__global__ __launch_bounds__(256)
void conv_k(const float* __restrict__ K, unsigned short* __restrict__ Kp)
{
  const int idx = blockIdx.x * 256 + threadIdx.x;  // 262144 total
  const int lam = idx & 63, f = (idx >> 6) & 1, kt = (idx >> 7) & (kNT - 1),
            b = idx >> 14;
  const int l15 = lam & 15, kg = lam >> 4;
  const float* src = K + ((size_t)(b * kSK + kt * 16 + l15) * kD) + f * 32 + kg * 8;
  u16x8 o;
#pragma unroll
  for (int e = 0; e < 8; ++e) {
    union { float f; unsigned int u; } cv; cv.f = src[e];
    // round-to-nearest-even bf16
    unsigned int r = cv.u + 0x7fff + ((cv.u >> 16) & 1);
    o[e] = (unsigned short)(r >> 16);
  }
  *reinterpret_cast<u16x8*>(Kp + (size_t)idx * 8) = o;
}

// ---- setup kernel 2: V[b][key][d] f32 -> Vp transposed f16 frag-ordered ----
// Vp[((b*kNT + t)*4 + dblk)*64 + lane][4] ; lane=(kg*16+l15) holds
// V[t*16+kg*4+e][dblk*16+l15], e=0..3. Main-kernel load = 1 dwordx2/lane.
__global__ __launch_bounds__(256)
void conv_v(const float* __restrict__ V, _Float16* __restrict__ Vp)
{
  const int idx = blockIdx.x * 256 + threadIdx.x;  // 524288 total
  const int lam = idx & 63, dblk = (idx >> 6) & 3, t = (idx >> 8) & (kNT - 1),
            b = idx >> 15;
  const int l15 = lam & 15, kg = lam >> 4;
  f16x4 o;
#pragma unroll
  for (int e = 0; e < 4; ++e)
    o[e] = (_Float16)V[((size_t)(b * kSK + t * 16 + kg * 4 + e) * kD) + dblk * 16 + l15];
  *reinterpret_cast<f16x4*>(Vp + (size_t)idx * 4) = o;
}

// ---- main: register-resident-P fused attention, hand-pipelined P1 ----
__global__ __launch_bounds__(256, 3)
void sdpa_main(const float* __restrict__ Qg, const unsigned short* __restrict__ Kp,
               const _Float16* __restrict__ Vp, const int* __restrict__ Mg,
               float* __restrict__ ctxOut, float* __restrict__ attnOut)
{
  __shared__ float sums[kNW][kQB];
  __shared__ __align__(16) float cpart[kNW][kQB][kCStride];

  const int tid  = threadIdx.x;
  const int wid  = tid >> 6;           // 0..3
  const int lane = tid & 63;
  const int l15  = lane & 15;
  const int kg   = lane >> 4;

  // XCD-bijective swizzle: 2048 wgs = 8 XCDs x 256 contiguous (2 batches/XCD).
  const int wg = (blockIdx.x & 7) * 256 + (blockIdx.x >> 3);
  const int b  = wg >> 7;
  const int q0 = (wg & 127) * kQB;

  const float* Qb = Qg + (size_t)b * kSQ * kD;
  const int qrow  = q0 + l15;
  const int kbase = wid * (kTPW * 16);
  const int gt0   = wid * kTPW;        // first global 16-key tile of this wave

  const unsigned short* Kpb = Kp + (size_t)b * kNT * 2 * 64 * 8;
  const _Float16*       Vpb = Vp + (size_t)b * kNT * 4 * 64 * 4;
  const int* mrow = Mg + (size_t)b * kSQ * kSK + (size_t)qrow * kSK + kbase;

  // Q fragment (B operand of swapped QK^T): col=l15=q, k=kg*8+e.
  bf16x8 qf0, qf1;
  {
    const float* qp = Qb + (size_t)qrow * kD + kg * 8;
#pragma unroll
    for (int e = 0; e < 8; ++e) { qf0[e] = (__bf16)qp[e]; qf1[e] = (__bf16)qp[32 + e]; }
  }

  auto kfrag = [&](int t, int f) {
    return *reinterpret_cast<const bf16x8*>(
        Kpb + (((size_t)(gt0 + t) * 2 + f) * 64 + lane) * 8);
  };

  // ---- P1: QK^T + mask + exp, 6-deep mask pipeline, 1-ahead K ----
  f16x4 pb[kTPW];
  float lsum = 0.f;
  i32x4 mbuf[6];
  bf16x8 kb0[2], kb1[2];
#pragma unroll
  for (int p = 0; p < 6; ++p)
    mbuf[p] = *reinterpret_cast<const i32x4*>(mrow + p * 16 + kg * 4);
  kb0[0] = kfrag(0, 0); kb1[0] = kfrag(0, 1);
#pragma unroll
  for (int t = 0; t < kTPW; ++t) {
    const int cur = t & 1, nxt = cur ^ 1;
    if (t + 1 < kTPW) { kb0[nxt] = kfrag(t + 1, 0); kb1[nxt] = kfrag(t + 1, 1); }
    f32x4 acc = {0.f, 0.f, 0.f, 0.f};
    acc = __builtin_amdgcn_mfma_f32_16x16x32_bf16(kb0[cur], qf0, acc, 0, 0, 0);
    acc = __builtin_amdgcn_mfma_f32_16x16x32_bf16(kb1[cur], qf1, acc, 0, 0, 0);
    const i32x4 mv = mbuf[t % 6];
    if (t + 6 < kTPW)
      mbuf[t % 6] = *reinterpret_cast<const i32x4*>(mrow + (t + 6) * 16 + kg * 4);
    f16x4 p4;
#pragma unroll
    for (int r = 0; r < 4; ++r) {
      const float pv = mv[r] ? 0.f : __builtin_amdgcn_exp2f(acc[r] * kScaleLog2e);
      lsum += pv;
      p4[r] = (_Float16)pv;
    }
    pb[t] = p4;
  }
  lsum += __shfl_xor(lsum, 16, 64);
  lsum += __shfl_xor(lsum, 32, 64);
  if (lane < 16) sums[wid][l15] = lsum;
  __syncthreads();

  float lden = 0.f;
#pragma unroll
  for (int w = 0; w < kNW; ++w) lden += sums[w][l15];
  const float inv = 1.0f / lden;

  // ---- P2: attn stores straight from registers (fire-and-forget) ----
  {
    float* arow = attnOut + ((size_t)b * kSQ + qrow) * kSK + kbase;
#pragma unroll
    for (int t = 0; t < kTPW; ++t) {
      float4 o;
      o.x = (float)pb[t][0] * inv; o.y = (float)pb[t][1] * inv;
      o.z = (float)pb[t][2] * inv; o.w = (float)pb[t][3] * inv;
      *reinterpret_cast<float4*>(arow + t * 16 + kg * 4) = o;
    }
  }

  // ---- P3: PV via 16x16x16 f16; pb[t] is the B operand verbatim ----
  f32x4 cacc[4];
#pragma unroll
  for (int d = 0; d < 4; ++d) cacc[d] = f32x4{0.f, 0.f, 0.f, 0.f};
#pragma unroll
  for (int t = 0; t < kTPW; ++t) {
    const f16x4 pfrag = pb[t];
    const _Float16* vb = Vpb + ((size_t)(gt0 + t) * 4 * 64 + lane) * 4;
#pragma unroll
    for (int dblk = 0; dblk < 4; ++dblk) {
      const f16x4 vf = *reinterpret_cast<const f16x4*>(vb + (size_t)dblk * 64 * 4);
      cacc[dblk] = __builtin_amdgcn_mfma_f32_16x16x16f16(vf, pfrag, cacc[dblk], 0, 0, 0);
    }
  }
#pragma unroll
  for (int dblk = 0; dblk < 4; ++dblk)
    *reinterpret_cast<f32x4*>(&cpart[wid][l15][dblk * 16 + kg * 4]) = cacc[dblk];
  __syncthreads();

  // ---- P4: cross-wave reduce + scale + ctx store (all 256 threads) ----
  {
    const int q = tid >> 4;
    const int d = (tid & 15) * 4;
    float4 o = make_float4(0.f, 0.f, 0.f, 0.f);
#pragma unroll
    for (int w = 0; w < kNW; ++w) {
      const float4 p = *reinterpret_cast<const float4*>(&cpart[w][q][d]);
      o.x += p.x; o.y += p.y; o.z += p.z; o.w += p.w;
    }
    float l = 0.f;
#pragma unroll
    for (int w = 0; w < kNW; ++w) l += sums[w][q];
    const float iv = 1.0f / l;
    o.x *= iv; o.y *= iv; o.z *= iv; o.w *= iv;
    *reinterpret_cast<float4*>(ctxOut + ((size_t)b * kSQ + q0 + q) * kD + d) = o;
  }
}

extern "C" void kernel_launch(void* const* d_in, const int* in_sizes, int n_in,
                              void* d_out, int out_size, void* d_ws, size_t ws_size,
                              hipStream_t stream)
{
  const float* Q = (const float*)d_in[0];
  const float* K = (const float*)d_in[1];
  const float* V = (const float*)d_in[2];
  const int*   M = (const int*)d_in[3];   // bool mask pushed as 4-byte words
  float* ctx  = (float*)d_out;
  float* attn = (float*)d_out + (size_t)kB * kSQ * kD;

  unsigned short* Kp = (unsigned short*)d_ws;
  _Float16*       Vp = (_Float16*)((char*)d_ws + kVpOff);

  hipLaunchKernelGGL(conv_k, dim3(1024), dim3(256), 0, stream, K, Kp);
  hipLaunchKernelGGL(conv_v, dim3(2048), dim3(256), 0, stream, V, Vp);
  hipLaunchKernelGGL(sdpa_main, dim3(kB * kSQ / kQB), dim3(256), 0, stream,
                     Q, Kp, Vp, M, ctx, attn);
}

// Round 7
// 195.838 us; speedup vs baseline: 1.3626x; 1.0825x over previous
//
#include <hip/hip_runtime.h>
#include <hip/hip_bf16.h>

typedef __attribute__((ext_vector_type(8))) __bf16   bf16x8;
typedef __attribute__((ext_vector_type(4))) _Float16 f16x4;
typedef __attribute__((ext_vector_type(8))) _Float16 f16x8;
typedef __attribute__((ext_vector_type(4))) float    f32x4;
typedef __attribute__((ext_vector_type(4))) int      i32x4;
typedef __attribute__((ext_vector_type(8))) unsigned short u16x8;

namespace {
constexpr int kB   = 16;
constexpr int kSQ  = 2048;
constexpr int kSK  = 2048;
constexpr int kD   = 64;
constexpr int kQB  = 16;      // q-rows per workgroup
constexpr int kNW  = 4;       // waves per workgroup (256 threads)
constexpr int kTPW = 32;      // 16-key tiles per wave (512 keys/wave)
constexpr int kNT  = kSK / 16;            // 128 tiles per batch-row
constexpr int kCStride = 68;
constexpr float kScaleLog2e = 0.18033688011112042f; // (1/8)*log2(e)
// ws layout: Kp (bf16 frag-ordered) then Vp (f16 frag-ordered), 4 MB each.
constexpr size_t kKpElems = (size_t)kB * kNT * 2 * 64 * 8;  // ushort
constexpr size_t kVpOff   = kKpElems * 2;                   // bytes = 4 MB
}

// ---- setup kernel 1: K[b][key][d] f32 -> Kp fragment-ordered bf16 ----
// Kp[((b*kNT + kt)*2 + f)*64 + lane][8] ; lane=(kg*16+l15) holds
// K[kt*16+l15][f*32+kg*8 .. +8). Main-kernel load = 1 dwordx4/lane.
__global__ __launch_bounds__(256)
void conv_k(const float* __restrict__ K, unsigned short* __restrict__ Kp)
{
  const int idx = blockIdx.x * 256 + threadIdx.x;  // 262144 total
  const int lam = idx & 63, f = (idx >> 6) & 1, kt = (idx >> 7) & (kNT - 1),
            b = idx >> 14;
  const int l15 = lam & 15, kg = lam >> 4;
  const float* src = K + ((size_t)(b * kSK + kt * 16 + l15) * kD) + f * 32 + kg * 8;
  u16x8 o;
#pragma unroll
  for (int e = 0; e < 8; ++e) {
    union { float f; unsigned int u; } cv; cv.f = src[e];
    unsigned int r = cv.u + 0x7fff + ((cv.u >> 16) & 1);  // RNE bf16
    o[e] = (unsigned short)(r >> 16);
  }
  *reinterpret_cast<u16x8*>(Kp + (size_t)idx * 8) = o;
}

// ---- setup kernel 2: V -> Vp, f16, dblk-PAIR packed ----
// Vp[(((b*kNT+t)*64 + lam)*2 + h)*8] : f16x8 = {dblk=2h: e=0..3, dblk=2h+1: e=0..3}
// where element(dblk,e) = V[t*16+kg*4+e][dblk*16+l15], lam=(kg*16+l15).
// Main-kernel P3 load = 2 dwordx4 per (tile,lane) covering all 4 dblks.
__global__ __launch_bounds__(256)
void conv_v(const float* __restrict__ V, _Float16* __restrict__ Vp)
{
  const int idx = blockIdx.x * 256 + threadIdx.x;  // 262144 total
  const int h = idx & 1, lam = (idx >> 1) & 63, t = (idx >> 7) & (kNT - 1),
            b = idx >> 14;
  const int l15 = lam & 15, kg = lam >> 4;
  f16x8 o;
#pragma unroll
  for (int j = 0; j < 2; ++j)
#pragma unroll
    for (int e = 0; e < 4; ++e)
      o[j * 4 + e] = (_Float16)
          V[((size_t)(b * kSK + t * 16 + kg * 4 + e) * kD) + (2 * h + j) * 16 + l15];
  *reinterpret_cast<f16x8*>(Vp + (size_t)idx * 8) = o;
}

// ---- main: register-resident-P fused attention ----
__global__ __launch_bounds__(256, 3)
void sdpa_main(const float* __restrict__ Qg, const unsigned short* __restrict__ Kp,
               const _Float16* __restrict__ Vp, const int* __restrict__ Mg,
               float* __restrict__ ctxOut, float* __restrict__ attnOut)
{
  __shared__ float sums[kNW][kQB];
  __shared__ __align__(16) float cpart[kNW][kQB][kCStride];
  __shared__ __align__(16) char stg[kNW * 2048];   // per-wave P2 bounce buffers

  const int tid  = threadIdx.x;
  const int wid  = tid >> 6;           // 0..3
  const int lane = tid & 63;
  const int l15  = lane & 15;
  const int kg   = lane >> 4;

  // XCD-bijective swizzle: 2048 wgs = 8 XCDs x 256 contiguous (2 batches/XCD).
  const int wg = (blockIdx.x & 7) * 256 + (blockIdx.x >> 3);
  const int b  = wg >> 7;
  const int q0 = (wg & 127) * kQB;

  const float* Qb = Qg + (size_t)b * kSQ * kD;
  const int qrow  = q0 + l15;
  const int kbase = wid * (kTPW * 16);
  const int gt0   = wid * kTPW;        // first global 16-key tile of this wave

  const unsigned short* Kpb = Kp + (size_t)b * kNT * 2 * 64 * 8;
  const _Float16*       Vpb = Vp + (size_t)b * kNT * 64 * 16;
  const int* mrow = Mg + (size_t)b * kSQ * kSK + (size_t)qrow * kSK + kbase;

  // Q fragment (B operand of swapped QK^T): col=l15=q, k=kg*8+e.
  bf16x8 qf0, qf1;
  {
    const float* qp = Qb + (size_t)qrow * kD + kg * 8;
#pragma unroll
    for (int e = 0; e < 8; ++e) { qf0[e] = (__bf16)qp[e]; qf1[e] = (__bf16)qp[32 + e]; }
  }

  auto kfrag = [&](int t, int f) {
    return *reinterpret_cast<const bf16x8*>(
        Kpb + (((size_t)(gt0 + t) * 2 + f) * 64 + lane) * 8);
  };

  // ---- P1: QK^T + mask + exp, 6-deep mask pipeline, 1-ahead K ----
  f16x4 pb[kTPW];
  float lsum = 0.f;
  i32x4 mbuf[6];
  bf16x8 kb0[2], kb1[2];
#pragma unroll
  for (int p = 0; p < 6; ++p)
    mbuf[p] = *reinterpret_cast<const i32x4*>(mrow + p * 16 + kg * 4);
  kb0[0] = kfrag(0, 0); kb1[0] = kfrag(0, 1);
#pragma unroll
  for (int t = 0; t < kTPW; ++t) {
    const int cur = t & 1, nxt = cur ^ 1;
    if (t + 1 < kTPW) { kb0[nxt] = kfrag(t + 1, 0); kb1[nxt] = kfrag(t + 1, 1); }
    f32x4 acc = {0.f, 0.f, 0.f, 0.f};
    acc = __builtin_amdgcn_mfma_f32_16x16x32_bf16(kb0[cur], qf0, acc, 0, 0, 0);
    acc = __builtin_amdgcn_mfma_f32_16x16x32_bf16(kb1[cur], qf1, acc, 0, 0, 0);
    const i32x4 mv = mbuf[t % 6];
    if (t + 6 < kTPW)
      mbuf[t % 6] = *reinterpret_cast<const i32x4*>(mrow + (t + 6) * 16 + kg * 4);
    f16x4 p4;
#pragma unroll
    for (int r = 0; r < 4; ++r) {
      const float pv = mv[r] ? 0.f : __builtin_amdgcn_exp2f(acc[r] * kScaleLog2e);
      lsum += pv;
      p4[r] = (_Float16)pv;
    }
    pb[t] = p4;
  }
  lsum += __shfl_xor(lsum, 16, 64);
  lsum += __shfl_xor(lsum, 32, 64);
  if (lane < 16) sums[wid][l15] = lsum;
  __syncthreads();

  // ---- P2: attn stores via per-wave LDS bounce -> full 128B-line stores ----
  // Read-back rows for this lane: r0 = lane>>3, r1 = r0+8; 8 lanes per row.
  {
    const int r0 = lane >> 3, r1 = r0 + 8;
    float la = 0.f, lb = 0.f;
#pragma unroll
    for (int w = 0; w < kNW; ++w) { la += sums[w][r0]; lb += sums[w][r1]; }
    const float invA = 1.0f / la, invB = 1.0f / lb;
    char* sw = stg + wid * 2048;
    const int cb = (lane & 7) * 16;                 // byte col offset in buffer
    float* arow0 = attnOut + ((size_t)b * kSQ + q0 + r0) * kSK + kbase + (lane & 7) * 8;
    float* arow1 = attnOut + ((size_t)b * kSQ + q0 + r1) * kSK + kbase + (lane & 7) * 8;
#pragma unroll
    for (int g = 0; g < 8; ++g) {                   // 4 tiles (64 cols) per group
#pragma unroll
      for (int tl = 0; tl < 4; ++tl) {
        const int byte = (l15 * 128 + tl * 32 + kg * 8) ^ ((l15 & 7) << 4);
        *reinterpret_cast<f16x4*>(sw + byte) = pb[g * 4 + tl];
      }
      const f16x8 x0 = *reinterpret_cast<const f16x8*>(
          sw + ((r0 * 128 + cb) ^ ((r0 & 7) << 4)));
      const f16x8 x1 = *reinterpret_cast<const f16x8*>(
          sw + ((r1 * 128 + cb) ^ ((r1 & 7) << 4)));
      float4 o0a, o0b, o1a, o1b;
      o0a.x = (float)x0[0] * invA; o0a.y = (float)x0[1] * invA;
      o0a.z = (float)x0[2] * invA; o0a.w = (float)x0[3] * invA;
      o0b.x = (float)x0[4] * invA; o0b.y = (float)x0[5] * invA;
      o0b.z = (float)x0[6] * invA; o0b.w = (float)x0[7] * invA;
      o1a.x = (float)x1[0] * invB; o1a.y = (float)x1[1] * invB;
      o1a.z = (float)x1[2] * invB; o1a.w = (float)x1[3] * invB;
      o1b.x = (float)x1[4] * invB; o1b.y = (float)x1[5] * invB;
      o1b.z = (float)x1[6] * invB; o1b.w = (float)x1[7] * invB;
      *reinterpret_cast<float4*>(arow0 + g * 64)     = o0a;
      *reinterpret_cast<float4*>(arow0 + g * 64 + 4) = o0b;
      *reinterpret_cast<float4*>(arow1 + g * 64)     = o1a;
      *reinterpret_cast<float4*>(arow1 + g * 64 + 4) = o1b;
    }
  }

  // ---- P3: PV via 16x16x16 f16; pb[t] is the B operand verbatim ----
  f32x4 cacc[4];
#pragma unroll
  for (int d = 0; d < 4; ++d) cacc[d] = f32x4{0.f, 0.f, 0.f, 0.f};
#pragma unroll
  for (int t = 0; t < kTPW; ++t) {
    const f16x4 pfrag = pb[t];
    const _Float16* vb = Vpb + ((size_t)(gt0 + t) * 64 + lane) * 16;
    union { f16x8 v; f16x4 h[2]; } u01, u23;
    u01.v = *reinterpret_cast<const f16x8*>(vb);
    u23.v = *reinterpret_cast<const f16x8*>(vb + 8);
    cacc[0] = __builtin_amdgcn_mfma_f32_16x16x16f16(u01.h[0], pfrag, cacc[0], 0, 0, 0);
    cacc[1] = __builtin_amdgcn_mfma_f32_16x16x16f16(u01.h[1], pfrag, cacc[1], 0, 0, 0);
    cacc[2] = __builtin_amdgcn_mfma_f32_16x16x16f16(u23.h[0], pfrag, cacc[2], 0, 0, 0);
    cacc[3] = __builtin_amdgcn_mfma_f32_16x16x16f16(u23.h[1], pfrag, cacc[3], 0, 0, 0);
  }
#pragma unroll
  for (int dblk = 0; dblk < 4; ++dblk)
    *reinterpret_cast<f32x4*>(&cpart[wid][l15][dblk * 16 + kg * 4]) = cacc[dblk];
  __syncthreads();

  // ---- P4: cross-wave reduce + scale + ctx store (all 256 threads) ----
  {
    const int q = tid >> 4;
    const int d = (tid & 15) * 4;
    float4 o = make_float4(0.f, 0.f, 0.f, 0.f);
#pragma unroll
    for (int w = 0; w < kNW; ++w) {
      const float4 p = *reinterpret_cast<const float4*>(&cpart[w][q][d]);
      o.x += p.x; o.y += p.y; o.z += p.z; o.w += p.w;
    }
    float l = 0.f;
#pragma unroll
    for (int w = 0; w < kNW; ++w) l += sums[w][q];
    const float iv = 1.0f / l;
    o.x *= iv; o.y *= iv; o.z *= iv; o.w *= iv;
    *reinterpret_cast<float4*>(ctxOut + ((size_t)b * kSQ + q0 + q) * kD + d) = o;
  }
}

extern "C" void kernel_launch(void* const* d_in, const int* in_sizes, int n_in,
                              void* d_out, int out_size, void* d_ws, size_t ws_size,
                              hipStream_t stream)
{
  const float* Q = (const float*)d_in[0];
  const float* K = (const float*)d_in[1];
  const float* V = (const float*)d_in[2];
  const int*   M = (const int*)d_in[3];   // bool mask pushed as 4-byte words
  float* ctx  = (float*)d_out;
  float* attn = (float*)d_out + (size_t)kB * kSQ * kD;

  unsigned short* Kp = (unsigned short*)d_ws;
  _Float16*       Vp = (_Float16*)((char*)d_ws + kVpOff);

  hipLaunchKernelGGL(conv_k, dim3(1024), dim3(256), 0, stream, K, Kp);
  hipLaunchKernelGGL(conv_v, dim3(1024), dim3(256), 0, stream, V, Vp);
  hipLaunchKernelGGL(sdpa_main, dim3(kB * kSQ / kQB), dim3(256), 0, stream,
                     Q, Kp, Vp, M, ctx, attn);
}

// Round 8
// 185.370 us; speedup vs baseline: 1.4395x; 1.0565x over previous
//
#include <hip/hip_runtime.h>
#include <hip/hip_bf16.h>

typedef __attribute__((ext_vector_type(8))) __bf16   bf16x8;
typedef __attribute__((ext_vector_type(4))) _Float16 f16x4;
typedef __attribute__((ext_vector_type(8))) _Float16 f16x8;
typedef __attribute__((ext_vector_type(4))) float    f32x4;
typedef __attribute__((ext_vector_type(4))) int      i32x4;
typedef __attribute__((ext_vector_type(8))) unsigned short u16x8;

namespace {
constexpr int kB   = 16;
constexpr int kSQ  = 2048;
constexpr int kSK  = 2048;
constexpr int kD   = 64;
constexpr int kQB  = 16;      // q-rows per workgroup
constexpr int kNW  = 4;       // waves per workgroup (256 threads)
constexpr int kTPW = 32;      // 16-key tiles per wave (512 keys/wave)
constexpr int kNT  = kSK / 16;            // 128 tiles per batch-row
constexpr int kCStride = 68;
constexpr int kStgStride = 144;           // bounce row stride (bytes)
constexpr float kScaleLog2e = 0.18033688011112042f; // (1/8)*log2(e)
// ws layout: Kp bf16 frags (4 MB) | Vp f16 frags (4 MB) | mask bits (8 MB)
constexpr size_t kVpOff   = 4u << 20;
constexpr size_t kBitsOff = 8u << 20;
}

// ---- setup 1: K[b][key][d] f32 -> Kp fragment-ordered bf16 ----
__global__ __launch_bounds__(256)
void conv_k(const float* __restrict__ K, unsigned short* __restrict__ Kp)
{
  const int idx = blockIdx.x * 256 + threadIdx.x;  // 262144
  const int lam = idx & 63, f = (idx >> 6) & 1, kt = (idx >> 7) & (kNT - 1),
            b = idx >> 14;
  const int l15 = lam & 15, kg = lam >> 4;
  const float* src = K + ((size_t)(b * kSK + kt * 16 + l15) * kD) + f * 32 + kg * 8;
  u16x8 o;
#pragma unroll
  for (int e = 0; e < 8; ++e) {
    union { float f; unsigned int u; } cv; cv.f = src[e];
    unsigned int r = cv.u + 0x7fff + ((cv.u >> 16) & 1);  // RNE bf16
    o[e] = (unsigned short)(r >> 16);
  }
  *reinterpret_cast<u16x8*>(Kp + (size_t)idx * 8) = o;
}

// ---- setup 2: V -> Vp f16, dblk-pair packed (2 dwordx4 per tile-lane) ----
__global__ __launch_bounds__(256)
void conv_v(const float* __restrict__ V, _Float16* __restrict__ Vp)
{
  const int idx = blockIdx.x * 256 + threadIdx.x;  // 262144
  const int h = idx & 1, lam = (idx >> 1) & 63, t = (idx >> 7) & (kNT - 1),
            b = idx >> 14;
  const int l15 = lam & 15, kg = lam >> 4;
  f16x8 o;
#pragma unroll
  for (int j = 0; j < 2; ++j)
#pragma unroll
    for (int e = 0; e < 4; ++e)
      o[j * 4 + e] = (_Float16)
          V[((size_t)(b * kSK + t * 16 + kg * 4 + e) * kD) + (2 * h + j) * 16 + l15];
  *reinterpret_cast<f16x8*>(Vp + (size_t)idx * 8) = o;
}

// ---- setup 3: int32 mask -> 1-bit mask via ballot (pure streaming) ----
// bit i of word w == (M[w*64+i] != 0). Wave j-loop: read 256B coalesced,
// ballot -> u64, lane j keeps word j; epilogue: 512B contiguous store.
__global__ __launch_bounds__(256)
void conv_m(const int* __restrict__ M, unsigned long long* __restrict__ bits)
{
  const int gtid = blockIdx.x * 256 + threadIdx.x;
  const int wv   = gtid >> 6;          // 0..16383
  const int lane = gtid & 63;
  const size_t ibase = (size_t)wv * 4096;
  unsigned long long myword = 0;
#pragma unroll
  for (int j = 0; j < 64; ++j) {
    const int v = M[ibase + (size_t)j * 64 + lane];
    const unsigned long long bb = __ballot(v != 0);
    myword = (lane == j) ? bb : myword;
  }
  bits[(size_t)wv * 64 + lane] = myword;
}

// ---- main: register-resident-P fused attention, bit-mask input ----
__global__ __launch_bounds__(256, 3)
void sdpa_main(const float* __restrict__ Qg, const unsigned short* __restrict__ Kp,
               const _Float16* __restrict__ Vp, const unsigned int* __restrict__ Mbits,
               float* __restrict__ ctxOut, float* __restrict__ attnOut)
{
  __shared__ float sums[kNW][kQB];
  __shared__ __align__(16) float cpart[kNW][kQB][kCStride];
  __shared__ __align__(16) char stg[kNW * kQB * kStgStride];  // 9216 B

  const int tid  = threadIdx.x;
  const int wid  = tid >> 6;           // 0..3
  const int lane = tid & 63;
  const int l15  = lane & 15;
  const int kg   = lane >> 4;

  // XCD-bijective swizzle: 2048 wgs = 8 XCDs x 256 contiguous (2 batches/XCD).
  const int wg = (blockIdx.x & 7) * 256 + (blockIdx.x >> 3);
  const int b  = wg >> 7;
  const int q0 = (wg & 127) * kQB;

  const float* Qb = Qg + (size_t)b * kSQ * kD;
  const int qrow  = q0 + l15;
  const int kbase = wid * (kTPW * 16);
  const int gt0   = wid * kTPW;

  const unsigned short* Kpb = Kp + (size_t)b * kNT * 2 * 64 * 8;
  const _Float16*       Vpb = Vp + (size_t)b * kNT * 64 * 16;

  // Q fragment (B operand of swapped QK^T): col=l15=q, k=kg*8+e.
  bf16x8 qf0, qf1;
  {
    const float* qp = Qb + (size_t)qrow * kD + kg * 8;
#pragma unroll
    for (int e = 0; e < 8; ++e) { qf0[e] = (__bf16)qp[e]; qf1[e] = (__bf16)qp[32 + e]; }
  }

  // mask bits: 16 u32 words cover this lane's 512 keys of row qrow (L2-hot)
  unsigned int mw[16];
  {
    const unsigned int* mwp = Mbits + ((size_t)(b * kSQ + qrow) * (kSK / 32))
                                     + (kbase >> 5);
#pragma unroll
    for (int i = 0; i < 4; ++i) {
      const i32x4 v = *reinterpret_cast<const i32x4*>(mwp + i * 4);
#pragma unroll
      for (int j = 0; j < 4; ++j) mw[i * 4 + j] = (unsigned int)v[j];
    }
  }

  auto kfrag = [&](int t, int f) {
    return *reinterpret_cast<const bf16x8*>(
        Kpb + (((size_t)(gt0 + t) * 2 + f) * 64 + lane) * 8);
  };

  // ---- P1: QK^T + bitmask + exp -> packed f16 P in registers ----
  f16x4 pb[kTPW];
  float lsum = 0.f;
  bf16x8 kb0[2], kb1[2];
  kb0[0] = kfrag(0, 0); kb1[0] = kfrag(0, 1);
#pragma unroll
  for (int t = 0; t < kTPW; ++t) {
    const int cur = t & 1, nxt = cur ^ 1;
    if (t + 1 < kTPW) { kb0[nxt] = kfrag(t + 1, 0); kb1[nxt] = kfrag(t + 1, 1); }
    f32x4 acc = {0.f, 0.f, 0.f, 0.f};
    acc = __builtin_amdgcn_mfma_f32_16x16x32_bf16(kb0[cur], qf0, acc, 0, 0, 0);
    acc = __builtin_amdgcn_mfma_f32_16x16x32_bf16(kb1[cur], qf1, acc, 0, 0, 0);
    const unsigned int bits4 =
        (mw[t >> 1] >> (((t & 1) << 4) + (kg << 2))) & 15u;
    f16x4 p4;
#pragma unroll
    for (int r = 0; r < 4; ++r) {
      const float pv = ((bits4 >> r) & 1u)
                           ? 0.f
                           : __builtin_amdgcn_exp2f(acc[r] * kScaleLog2e);
      lsum += pv;
      p4[r] = (_Float16)pv;
    }
    pb[t] = p4;
  }
  lsum += __shfl_xor(lsum, 16, 64);
  lsum += __shfl_xor(lsum, 32, 64);
  if (lane < 16) sums[wid][l15] = lsum;
  __syncthreads();

  // ---- P2: attn stores via per-wave bounce; full 128B line per instr ----
  {
    const int r0 = lane >> 3, r1 = r0 + 8;
    float la = 0.f, lb = 0.f;
#pragma unroll
    for (int w = 0; w < kNW; ++w) { la += sums[w][r0]; lb += sums[w][r1]; }
    const float invA = 1.0f / la, invB = 1.0f / lb;
    char* sw = stg + wid * (kQB * kStgStride);
    const int c8 = (lane & 7) * 8;      // byte col of this lane's f16x4
    float* arow0 = attnOut + ((size_t)b * kSQ + q0 + r0) * kSK + kbase;
    float* arow1 = attnOut + ((size_t)b * kSQ + q0 + r1) * kSK + kbase;
#pragma unroll
    for (int g = 0; g < 8; ++g) {       // 4 tiles (64 cols) per group
#pragma unroll
      for (int tl = 0; tl < 4; ++tl)
        *reinterpret_cast<f16x4*>(sw + l15 * kStgStride + tl * 32 + kg * 8)
            = pb[g * 4 + tl];
      const f16x4 x0a = *reinterpret_cast<const f16x4*>(sw + r0 * kStgStride + c8);
      const f16x4 x0b = *reinterpret_cast<const f16x4*>(sw + r0 * kStgStride + 64 + c8);
      const f16x4 x1a = *reinterpret_cast<const f16x4*>(sw + r1 * kStgStride + c8);
      const f16x4 x1b = *reinterpret_cast<const f16x4*>(sw + r1 * kStgStride + 64 + c8);
      float4 o;
      const int cA = g * 64 + (lane & 7) * 4;   // lanes 0..7 -> one full line
      o.x = (float)x0a[0] * invA; o.y = (float)x0a[1] * invA;
      o.z = (float)x0a[2] * invA; o.w = (float)x0a[3] * invA;
      *reinterpret_cast<float4*>(arow0 + cA) = o;
      o.x = (float)x0b[0] * invA; o.y = (float)x0b[1] * invA;
      o.z = (float)x0b[2] * invA; o.w = (float)x0b[3] * invA;
      *reinterpret_cast<float4*>(arow0 + cA + 32) = o;
      o.x = (float)x1a[0] * invB; o.y = (float)x1a[1] * invB;
      o.z = (float)x1a[2] * invB; o.w = (float)x1a[3] * invB;
      *reinterpret_cast<float4*>(arow1 + cA) = o;
      o.x = (float)x1b[0] * invB; o.y = (float)x1b[1] * invB;
      o.z = (float)x1b[2] * invB; o.w = (float)x1b[3] * invB;
      *reinterpret_cast<float4*>(arow1 + cA + 32) = o;
    }
  }

  // ---- P3: PV via 16x16x16 f16 (V prefetched 1 tile ahead) ----
  f32x4 cacc[4];
#pragma unroll
  for (int d = 0; d < 4; ++d) cacc[d] = f32x4{0.f, 0.f, 0.f, 0.f};
  f16x8 v01[2], v23[2];
  {
    const _Float16* vb = Vpb + ((size_t)gt0 * 64 + lane) * 16;
    v01[0] = *reinterpret_cast<const f16x8*>(vb);
    v23[0] = *reinterpret_cast<const f16x8*>(vb + 8);
  }
#pragma unroll
  for (int t = 0; t < kTPW; ++t) {
    const int cur = t & 1, nxt = cur ^ 1;
    if (t + 1 < kTPW) {
      const _Float16* vb = Vpb + ((size_t)(gt0 + t + 1) * 64 + lane) * 16;
      v01[nxt] = *reinterpret_cast<const f16x8*>(vb);
      v23[nxt] = *reinterpret_cast<const f16x8*>(vb + 8);
    }
    const f16x4 pfrag = pb[t];
    union { f16x8 v; f16x4 h[2]; } a, c;
    a.v = v01[cur]; c.v = v23[cur];
    cacc[0] = __builtin_amdgcn_mfma_f32_16x16x16f16(a.h[0], pfrag, cacc[0], 0, 0, 0);
    cacc[1] = __builtin_amdgcn_mfma_f32_16x16x16f16(a.h[1], pfrag, cacc[1], 0, 0, 0);
    cacc[2] = __builtin_amdgcn_mfma_f32_16x16x16f16(c.h[0], pfrag, cacc[2], 0, 0, 0);
    cacc[3] = __builtin_amdgcn_mfma_f32_16x16x16f16(c.h[1], pfrag, cacc[3], 0, 0, 0);
  }
#pragma unroll
  for (int dblk = 0; dblk < 4; ++dblk)
    *reinterpret_cast<f32x4*>(&cpart[wid][l15][dblk * 16 + kg * 4]) = cacc[dblk];
  __syncthreads();

  // ---- P4: cross-wave reduce + scale + ctx store ----
  {
    const int q = tid >> 4;
    const int d = (tid & 15) * 4;
    float4 o = make_float4(0.f, 0.f, 0.f, 0.f);
#pragma unroll
    for (int w = 0; w < kNW; ++w) {
      const float4 p = *reinterpret_cast<const float4*>(&cpart[w][q][d]);
      o.x += p.x; o.y += p.y; o.z += p.z; o.w += p.w;
    }
    float l = 0.f;
#pragma unroll
    for (int w = 0; w < kNW; ++w) l += sums[w][q];
    const float iv = 1.0f / l;
    o.x *= iv; o.y *= iv; o.z *= iv; o.w *= iv;
    *reinterpret_cast<float4*>(ctxOut + ((size_t)b * kSQ + q0 + q) * kD + d) = o;
  }
}

extern "C" void kernel_launch(void* const* d_in, const int* in_sizes, int n_in,
                              void* d_out, int out_size, void* d_ws, size_t ws_size,
                              hipStream_t stream)
{
  const float* Q = (const float*)d_in[0];
  const float* K = (const float*)d_in[1];
  const float* V = (const float*)d_in[2];
  const int*   M = (const int*)d_in[3];   // bool mask pushed as 4-byte words
  float* ctx  = (float*)d_out;
  float* attn = (float*)d_out + (size_t)kB * kSQ * kD;

  unsigned short*     Kp = (unsigned short*)d_ws;
  _Float16*           Vp = (_Float16*)((char*)d_ws + kVpOff);
  unsigned long long* Mb = (unsigned long long*)((char*)d_ws + kBitsOff);

  hipLaunchKernelGGL(conv_k, dim3(1024), dim3(256), 0, stream, K, Kp);
  hipLaunchKernelGGL(conv_v, dim3(1024), dim3(256), 0, stream, V, Vp);
  hipLaunchKernelGGL(conv_m, dim3(4096), dim3(256), 0, stream, M, Mb);
  hipLaunchKernelGGL(sdpa_main, dim3(kB * kSQ / kQB), dim3(256), 0, stream,
                     Q, Kp, Vp, (const unsigned int*)Mb, ctx, attn);
}